// Round 6
// baseline (377.295 us; speedup 1.0000x reference)
//
#include <hip/hip_runtime.h>
#include <hip/hip_bf16.h>

// AtomFeatureEmbedder on MI355X (gfx950).
// Inputs: float32 (+ uid int32). Outputs: float32, concat
// [cl (1,2048,128), plm (1,2048,2048,16)].
//
// R5 post-mortem: single-kernel fill+compute plateaued ~2.3x over the write
// floor. This version splits into two ordered launches:
//   K1: pure grid-stride float4 zero-fill of the whole 269.5 MB output —
//       byte-for-byte the structure of the harness fill kernel that sustains
//       6.5 TB/s on this buffer (no LDS / barriers / loads).
//   K2: cl GEMM (256 blocks) + uid-match scatter (32 blocks; ~16K matching
//       pairs -> ~1 MB of 64 B writes overwriting K1's zeros).

#define N_ATOMS   2048
#define C_ATOM    128
#define C_PAIR    16
#define CL_ATOMS  8                      // atoms per cl block
#define CL_BLOCKS (N_ATOMS / CL_ATOMS)   // 256
#define KP        392                    // 390 features padded to multiple of 4
#define SC_BLOCKS 32                     // scatter blocks (64 rows each)
#define SC_ROWS   (N_ATOMS / SC_BLOCKS)  // 64

extern "C" __global__ __launch_bounds__(256)
void fill_zero_kernel(float4* __restrict__ p, int n4) {
    const float4 z = make_float4(0.f, 0.f, 0.f, 0.f);
    int i = blockIdx.x * 256 + threadIdx.x;
    const int stride = gridDim.x * 256;
    for (; i < n4; i += stride) p[i] = z;
}

extern "C" __global__ __launch_bounds__(256)
void compute_kernel(const float* __restrict__ pos,      // [2048,3] f32
                    const float* __restrict__ mask,     // [2048]
                    const float* __restrict__ elem,     // [2048,128]
                    const float* __restrict__ charge,   // [2048]
                    const float* __restrict__ chars,    // [2048,256]
                    const int*   __restrict__ uid,      // [2048] int32
                    const float* __restrict__ Wf,       // [390,128]
                    const float* __restrict__ Woff,     // [3,16]
                    const float* __restrict__ Winv,     // [1,16]
                    const float* __restrict__ Wmask,    // [1,16]
                    float* __restrict__ out)            // cl then plm
{
    const int tid = threadIdx.x;

    if (blockIdx.x < CL_BLOCKS) {
        // ---------------- cl = feats @ W_feats ----------------
        __shared__ __align__(16) float sf[CL_ATOMS * KP];
        const int atom0 = blockIdx.x * CL_ATOMS;

        for (int idx = tid; idx < CL_ATOMS * KP; idx += 256) {
            const int a = idx / KP;
            const int k = idx - a * KP;
            const int ga = atom0 + a;
            float v = 0.0f;
            if (k < 3)          v = pos[ga * 3 + k];
            else if (k == 3)    v = mask[ga];
            else if (k < 132)   v = elem[ga * 128 + (k - 4)];
            else if (k == 132)  v = charge[ga];
            else if (k < 389)   v = chars[ga * 256 + (k - 133)];
            else if (k == 389)  v = (float)uid[ga];
            sf[idx] = v;
        }
        __syncthreads();

        const int col = tid & 127;
        const int sub = tid >> 7;          // 0 or 1 -> atoms [sub*4, sub*4+4)
        const float* sfa = &sf[sub * 4 * KP];
        float acc[4] = {0.f, 0.f, 0.f, 0.f};

        for (int k0 = 0; k0 < 388; k0 += 4) {
            const float w0 = Wf[(k0 + 0) * 128 + col];
            const float w1 = Wf[(k0 + 1) * 128 + col];
            const float w2 = Wf[(k0 + 2) * 128 + col];
            const float w3 = Wf[(k0 + 3) * 128 + col];
            #pragma unroll
            for (int a = 0; a < 4; a++) {
                const float4 f = *(const float4*)&sfa[a * KP + k0];
                acc[a] += f.x * w0 + f.y * w1 + f.z * w2 + f.w * w3;
            }
        }
        {   // tail: k = 388, 389
            const float w0 = Wf[388 * 128 + col];
            const float w1 = Wf[389 * 128 + col];
            #pragma unroll
            for (int a = 0; a < 4; a++) {
                const float2 f = *(const float2*)&sfa[a * KP + 388];
                acc[a] += f.x * w0 + f.y * w1;
            }
        }
        #pragma unroll
        for (int a = 0; a < 4; a++) {
            const int ga = atom0 + sub * 4 + a;
            out[ga * 128 + col] = acc[a];
        }
    } else {
        // ---------------- scatter: overwrite uid-matches ----------------
        const int sb   = blockIdx.x - CL_BLOCKS;   // [0, 32)
        const int lane = tid & 63;
        const int wv   = tid >> 6;                 // wave id 0..3

        __shared__ float sw[80];   // wox[16], woy[16], woz[16], wiv[16], wmk[16]
        if (tid < 80) {
            float v;
            if (tid < 48)      v = Woff[tid];
            else if (tid < 64) v = Winv[tid - 48];
            else               v = Wmask[tid - 64];
            sw[tid] = v;
        }
        __syncthreads();

        float* plm = out + (size_t)N_ATOMS * C_ATOM;
        const int4* uid4 = (const int4*)uid;

        for (int r = wv; r < SC_ROWS; r += 4) {
            const int l  = sb * SC_ROWS + r;
            const int ul = uid[l];
            const float lx = pos[l * 3 + 0];
            const float ly = pos[l * 3 + 1];
            const float lz = pos[l * 3 + 2];

            for (int it = 0; it < 8; it++) {           // 8*64 lanes*4 = 2048 uids
                const int4 u = uid4[it * 64 + lane];
                const int mb = (it * 64 + lane) * 4;
                #pragma unroll
                for (int s = 0; s < 4; s++) {
                    const int um = (s == 0) ? u.x : (s == 1) ? u.y
                                 : (s == 2) ? u.z : u.w;
                    if (um == ul) {
                        const int m = mb + s;
                        const float dx = pos[m * 3 + 0] - lx;
                        const float dy = pos[m * 3 + 1] - ly;
                        const float dz = pos[m * 3 + 2] - lz;
                        const float invd =
                            1.0f / (1.0f + sqrtf(dx * dx + dy * dy + dz * dz));
                        float* dst = plm + ((size_t)l * N_ATOMS + m) * C_PAIR;
                        #pragma unroll
                        for (int g = 0; g < 4; g++) {
                            float4 v;
                            v.x = dx * sw[4*g+0] + dy * sw[16+4*g+0] + dz * sw[32+4*g+0]
                                + invd * sw[48+4*g+0] + sw[64+4*g+0];
                            v.y = dx * sw[4*g+1] + dy * sw[16+4*g+1] + dz * sw[32+4*g+1]
                                + invd * sw[48+4*g+1] + sw[64+4*g+1];
                            v.z = dx * sw[4*g+2] + dy * sw[16+4*g+2] + dz * sw[32+4*g+2]
                                + invd * sw[48+4*g+2] + sw[64+4*g+2];
                            v.w = dx * sw[4*g+3] + dy * sw[16+4*g+3] + dz * sw[32+4*g+3]
                                + invd * sw[48+4*g+3] + sw[64+4*g+3];
                            *(float4*)(dst + 4 * g) = v;
                        }
                    }
                }
            }
        }
    }
}

extern "C" void kernel_launch(void* const* d_in, const int* in_sizes, int n_in,
                              void* d_out, int out_size, void* d_ws, size_t ws_size,
                              hipStream_t stream) {
    const float* pos    = (const float*)d_in[0];
    const float* rmask  = (const float*)d_in[1];
    const float* elem   = (const float*)d_in[2];
    const float* charge = (const float*)d_in[3];
    const float* chars  = (const float*)d_in[4];
    const int*   uid    = (const int*)d_in[5];
    const float* Wf     = (const float*)d_in[6];
    const float* Woff   = (const float*)d_in[7];
    const float* Winv   = (const float*)d_in[8];
    const float* Wmask  = (const float*)d_in[9];
    float* out = (float*)d_out;

    // K1: zero the whole output (269.5 MB) at fill rate.
    const int n4 = out_size / 4;
    fill_zero_kernel<<<4096, 256, 0, stream>>>((float4*)out, n4);

    // K2: cl GEMM + match scatter (ordered after K1 on the stream).
    compute_kernel<<<CL_BLOCKS + SC_BLOCKS, 256, 0, stream>>>(
        pos, rmask, elem, charge, chars, uid, Wf, Woff, Winv, Wmask, out);
}

// Round 7
// 316.286 us; speedup vs baseline: 1.1929x; 1.1929x over previous
//
#include <hip/hip_runtime.h>
#include <hip/hip_bf16.h>

// AtomFeatureEmbedder on MI355X (gfx950).
// Inputs: float32 (+ uid int32). Outputs: float32, concat
// [cl (1,2048,128), plm (1,2048,2048,16)].
//
// Structure (R7):
//   K1: pure grid-stride float4 zero-fill of the 269.5 MB output (~41 us at
//       the 6.5 TB/s the harness's own fill sustains on this buffer).
//   K2: cl GEMM (256 blocks) + per-row uid-match scatter (2048 blocks).
// R6 post-mortem: scatter with 32 blocks + per-match LDS weight reads cost
// ~125 us (80 dependent ds_reads per match body, 64x too little block
// parallelism). Fix: one block per row, match list in LDS, 4 threads per
// match with their 20 weight floats in REGISTERS (loaded pre-barrier).

#define N_ATOMS   2048
#define C_ATOM    128
#define C_PAIR    16
#define CL_ATOMS  8                      // atoms per cl block
#define CL_BLOCKS (N_ATOMS / CL_ATOMS)   // 256
#define KP        392                    // 390 features padded to multiple of 4

extern "C" __global__ __launch_bounds__(256)
void fill_zero_kernel(float4* __restrict__ p, int n4) {
    const float4 z = make_float4(0.f, 0.f, 0.f, 0.f);
    int i = blockIdx.x * 256 + threadIdx.x;
    const int stride = gridDim.x * 256;
    for (; i < n4; i += stride) p[i] = z;
}

extern "C" __global__ __launch_bounds__(256)
void compute_kernel(const float* __restrict__ pos,      // [2048,3] f32
                    const float* __restrict__ mask,     // [2048]
                    const float* __restrict__ elem,     // [2048,128]
                    const float* __restrict__ charge,   // [2048]
                    const float* __restrict__ chars,    // [2048,256]
                    const int*   __restrict__ uid,      // [2048] int32
                    const float* __restrict__ Wf,       // [390,128]
                    const float* __restrict__ Woff,     // [3,16]
                    const float* __restrict__ Winv,     // [1,16]
                    const float* __restrict__ Wmask,    // [1,16]
                    float* __restrict__ out)            // cl then plm
{
    const int tid = threadIdx.x;

    if (blockIdx.x < CL_BLOCKS) {
        // ---------------- cl = feats @ W_feats ----------------
        __shared__ __align__(16) float sf[CL_ATOMS * KP];
        const int atom0 = blockIdx.x * CL_ATOMS;

        for (int idx = tid; idx < CL_ATOMS * KP; idx += 256) {
            const int a = idx / KP;
            const int k = idx - a * KP;
            const int ga = atom0 + a;
            float v = 0.0f;
            if (k < 3)          v = pos[ga * 3 + k];
            else if (k == 3)    v = mask[ga];
            else if (k < 132)   v = elem[ga * 128 + (k - 4)];
            else if (k == 132)  v = charge[ga];
            else if (k < 389)   v = chars[ga * 256 + (k - 133)];
            else if (k == 389)  v = (float)uid[ga];
            sf[idx] = v;
        }
        __syncthreads();

        const int col = tid & 127;
        const int sub = tid >> 7;          // 0 or 1 -> atoms [sub*4, sub*4+4)
        const float* sfa = &sf[sub * 4 * KP];
        float acc[4] = {0.f, 0.f, 0.f, 0.f};

        for (int k0 = 0; k0 < 388; k0 += 4) {
            const float w0 = Wf[(k0 + 0) * 128 + col];
            const float w1 = Wf[(k0 + 1) * 128 + col];
            const float w2 = Wf[(k0 + 2) * 128 + col];
            const float w3 = Wf[(k0 + 3) * 128 + col];
            #pragma unroll
            for (int a = 0; a < 4; a++) {
                const float4 f = *(const float4*)&sfa[a * KP + k0];
                acc[a] += f.x * w0 + f.y * w1 + f.z * w2 + f.w * w3;
            }
        }
        {   // tail: k = 388, 389
            const float w0 = Wf[388 * 128 + col];
            const float w1 = Wf[389 * 128 + col];
            #pragma unroll
            for (int a = 0; a < 4; a++) {
                const float2 f = *(const float2*)&sfa[a * KP + 388];
                acc[a] += f.x * w0 + f.y * w1;
            }
        }
        #pragma unroll
        for (int a = 0; a < 4; a++) {
            const int ga = atom0 + sub * 4 + a;
            out[ga * 128 + col] = acc[a];
        }
    } else {
        // ------------- scatter: one block per row l -------------
        const int l  = blockIdx.x - CL_BLOCKS;   // [0, 2048)
        const int ul = uid[l];

        // Register weights for this thread's channel group (issued early;
        // latency hidden behind phase A + barrier).
        const int g = tid & 3;
        const float4 wx = *(const float4*)&Woff[4 * g];
        const float4 wy = *(const float4*)&Woff[16 + 4 * g];
        const float4 wz = *(const float4*)&Woff[32 + 4 * g];
        const float4 wi = *(const float4*)&Winv[4 * g];
        const float4 wm = *(const float4*)&Wmask[4 * g];
        const float lx = pos[l * 3 + 0];
        const float ly = pos[l * 3 + 1];
        const float lz = pos[l * 3 + 2];

        __shared__ int s_cnt;
        __shared__ int s_list[N_ATOMS];          // worst case: all match
        if (tid == 0) s_cnt = 0;
        __syncthreads();

        // --- phase A: scan 2048 uids, list matches ---
        {
            const int4* uid4 = (const int4*)uid;
            #pragma unroll
            for (int h = 0; h < 2; h++) {
                const int t4 = h * 256 + tid;    // int4 index
                const int4 u = uid4[t4];
                const int m0 = 4 * t4;
                if (u.x == ul) { int i = atomicAdd(&s_cnt, 1); s_list[i] = m0 + 0; }
                if (u.y == ul) { int i = atomicAdd(&s_cnt, 1); s_list[i] = m0 + 1; }
                if (u.z == ul) { int i = atomicAdd(&s_cnt, 1); s_list[i] = m0 + 2; }
                if (u.w == ul) { int i = atomicAdd(&s_cnt, 1); s_list[i] = m0 + 3; }
            }
        }
        __syncthreads();

        // --- phase B: 4 threads per match entry ---
        const int cnt = s_cnt;
        float4* rowp = (float4*)(out + (size_t)N_ATOMS * C_ATOM
                                     + (size_t)l * N_ATOMS * C_PAIR);
        for (int e = (tid >> 2); e < cnt; e += 64) {
            const int m = s_list[e];
            const float dx = pos[m * 3 + 0] - lx;
            const float dy = pos[m * 3 + 1] - ly;
            const float dz = pos[m * 3 + 2] - lz;
            const float invd = 1.0f / (1.0f + sqrtf(dx * dx + dy * dy + dz * dz));
            float4 v;
            v.x = dx * wx.x + dy * wy.x + dz * wz.x + invd * wi.x + wm.x;
            v.y = dx * wx.y + dy * wy.y + dz * wz.y + invd * wi.y + wm.y;
            v.z = dx * wx.z + dy * wy.z + dz * wz.z + invd * wi.z + wm.z;
            v.w = dx * wx.w + dy * wy.w + dz * wz.w + invd * wi.w + wm.w;
            rowp[m * 4 + g] = v;
        }
    }
}

extern "C" void kernel_launch(void* const* d_in, const int* in_sizes, int n_in,
                              void* d_out, int out_size, void* d_ws, size_t ws_size,
                              hipStream_t stream) {
    const float* pos    = (const float*)d_in[0];
    const float* rmask  = (const float*)d_in[1];
    const float* elem   = (const float*)d_in[2];
    const float* charge = (const float*)d_in[3];
    const float* chars  = (const float*)d_in[4];
    const int*   uid    = (const int*)d_in[5];
    const float* Wf     = (const float*)d_in[6];
    const float* Woff   = (const float*)d_in[7];
    const float* Winv   = (const float*)d_in[8];
    const float* Wmask  = (const float*)d_in[9];
    float* out = (float*)d_out;

    // K1: zero the whole output (269.5 MB) at fill rate.
    const int n4 = out_size / 4;
    fill_zero_kernel<<<4096, 256, 0, stream>>>((float4*)out, n4);

    // K2: cl GEMM + per-row match scatter (ordered after K1 on the stream).
    compute_kernel<<<CL_BLOCKS + N_ATOMS, 256, 0, stream>>>(
        pos, rmask, elem, charge, chars, uid, Wf, Woff, Winv, Wmask, out);
}